// Round 1
// baseline (414.546 us; speedup 1.0000x reference)
//
#include <hip/hip_runtime.h>
#include <math.h>

namespace {

constexpr int NF   = 256;   // n_feature / tokens
constexpr int EH   = 128;   // embedder hidden
constexpr int E    = 64;    // embedded dim
constexpr int H    = 64;    // lstm size
constexpr int SHD  = 256;   // shared hidden
constexpr int SD   = 128;   // shared dim
constexpr int NA   = 257;   // n_action
constexpr int NSHUF = 4;

__global__ __launch_bounds__(256) void seqnet(
    const float* __restrict__ state, const int* __restrict__ acquired,
    const float* __restrict__ We1, const float* __restrict__ be1,
    const float* __restrict__ We2, const float* __restrict__ be2,
    const float* __restrict__ Wih, const float* __restrict__ Whh,
    const float* __restrict__ bih, const float* __restrict__ bhh,
    const float* __restrict__ Ws1, const float* __restrict__ bs1,
    const float* __restrict__ Ws2, const float* __restrict__ bs2,
    const float* __restrict__ Wp1, const float* __restrict__ bp1,
    const float* __restrict__ Wp2, const float* __restrict__ bp2,
    const float* __restrict__ Wv1, const float* __restrict__ bv1,
    const float* __restrict__ Wv2, const float* __restrict__ bv2,
    float* __restrict__ out)
{
  const int b    = blockIdx.x;
  const int t    = threadIdx.x;
  const int lane = t & 63;
  const int wid  = t >> 6;

  __shared__ int   id_l[NF];      // sorted one-hot id (pos+1) for rank l
  __shared__ float val_l[NF];     // sorted state value for rank l
  __shared__ int   wcnt[4];
  __shared__ float wredf[4];
  __shared__ float qt_s[H];
  __shared__ float ct_s[H];
  __shared__ float att_s[E];
  __shared__ float gates_s[4 * H];
  __shared__ float part[4][E];
  __shared__ float t1_s[SHD];
  __shared__ float sh_s[SD];
  __shared__ float a1_s[SD];
  __shared__ float v1_s[SD];
  __shared__ float v_scalar;

  // ---------------- phase 0: closed-form "argsort" ----------------
  // descending stable sort of acquired*(i+1): acquired indices, largest first.
  const int ai = (acquired[b * NF + t] != 0) ? 1 : 0;
  const unsigned long long mask = __ballot(ai);
  const int pin = __popcll(mask & ((1ull << lane) - 1ull));
  if (lane == 0) wcnt[wid] = __popcll(mask);
  if (t < H) { qt_s[t] = 0.f; ct_s[t] = 0.f; att_s[t] = 0.f; }
  __syncthreads();
  int pexcl = pin;  // # acquired with index < t
  int L = 0;
  #pragma unroll
  for (int w = 0; w < 4; ++w) {
    const int c = wcnt[w];
    if (w < wid) pexcl += c;
    L += c;
  }
  if (ai) {
    const int rank = L - pexcl - 1;      // # acquired with index > t
    id_l[rank]  = t + 1;
    val_l[rank] = state[b * NF + t];
  }
  __syncthreads();

  // ---------------- phase 1: embedder (thread t == token t) ----------------
  // hid = relu(val*We1[0,:] + We1[id,:] + be1); emb = hid @ We2 + be2
  float emb[E];
  #pragma unroll
  for (int e = 0; e < E; ++e) emb[e] = 0.f;
  if (t < L) {
    const int   id = id_l[t];
    const float v  = val_l[t];
    const float* __restrict__ w1r = We1 + id * EH;
    for (int k = 0; k < EH; k += 4) {
      const float4 wr = *(const float4*)(w1r + k);
      const float4 w0 = *(const float4*)(We1 + k);   // row 0 (vals weight)
      const float4 bb = *(const float4*)(be1 + k);
      const float h0 = fmaxf(fmaf(v, w0.x, wr.x) + bb.x, 0.f);
      const float h1 = fmaxf(fmaf(v, w0.y, wr.y) + bb.y, 0.f);
      const float h2 = fmaxf(fmaf(v, w0.z, wr.z) + bb.z, 0.f);
      const float h3 = fmaxf(fmaf(v, w0.w, wr.w) + bb.w, 0.f);
      const float* __restrict__ w2r = We2 + k * E;   // uniform -> scalar loads
      #pragma unroll
      for (int e = 0; e < E; ++e) {
        float acc = emb[e];
        acc = fmaf(h0, w2r[e],         acc);
        acc = fmaf(h1, w2r[E + e],     acc);
        acc = fmaf(h2, w2r[2 * E + e], acc);
        acc = fmaf(h3, w2r[3 * E + e], acc);
        emb[e] = acc;
      }
    }
    #pragma unroll
    for (int e = 0; e < E; ++e) emb[e] += be2[e];
  }

  // ---------------- phase 2: attention + LSTM, N_SHUFFLE iters ----------------
  if (L > 0) {
    for (int it = 0; it < NSHUF; ++it) {
      // logits_t = emb_t . qt
      float lg = -1e30f;
      if (t < L) {
        lg = 0.f;
        #pragma unroll
        for (int e = 0; e < E; ++e) lg = fmaf(emb[e], qt_s[e], lg);
      }
      // block max
      float m = lg;
      #pragma unroll
      for (int d = 32; d > 0; d >>= 1) m = fmaxf(m, __shfl_xor(m, d));
      if (lane == 0) wredf[wid] = m;
      __syncthreads();
      m = fmaxf(fmaxf(wredf[0], wredf[1]), fmaxf(wredf[2], wredf[3]));
      __syncthreads();   // protect wredf reuse
      const float p = (t < L) ? expf(lg - m) : 0.f;
      float s = p;
      #pragma unroll
      for (int d = 32; d > 0; d >>= 1) s += __shfl_xor(s, d);
      if (lane == 0) wredf[wid] = s;
      __syncthreads();
      s = wredf[0] + wredf[1] + wredf[2] + wredf[3];
      const float w = p / s;

      // attended[e] = sum_t w_t * emb_t[e]: in-register butterfly transpose-reduce.
      float u[E];
      #pragma unroll
      for (int e = 0; e < E; ++e) u[e] = w * emb[e];
      #pragma unroll
      for (int step = 0; step < 6; ++step) {
        const int d = 32 >> step;
        const bool hi = (lane & d) != 0;
        #pragma unroll
        for (int i = 0; i < d; ++i) {         // all indices compile-time
          const float keep = hi ? u[i + d] : u[i];
          const float send = hi ? u[i] : u[i + d];
          u[i] = keep + __shfl_xor(send, d);
        }
      }
      part[wid][lane] = u[0];                 // per-wave column sums
      __syncthreads();
      if (t < E) att_s[t] = part[0][t] + part[1][t] + part[2][t] + part[3][t];
      __syncthreads();

      // gates[t] = att @ Wih[:,t] + qt @ Whh[:,t] + bih[t] + bhh[t]
      float g = bih[t] + bhh[t];
      for (int e = 0; e < E; ++e) g = fmaf(att_s[e], Wih[e * (4 * H) + t], g);
      for (int h = 0; h < H; ++h) g = fmaf(qt_s[h], Whh[h * (4 * H) + t], g);
      gates_s[t] = g;
      __syncthreads();
      if (t < H) {
        const float ig = gates_s[t];
        const float fg = gates_s[H + t];
        const float gg = gates_s[2 * H + t];
        const float og = gates_s[3 * H + t];
        const float si = 1.f / (1.f + expf(-ig));
        const float sf = 1.f / (1.f + expf(-fg));
        const float so = 1.f / (1.f + expf(-og));
        float c = ct_s[t];
        c = sf * c + si * tanhf(gg);
        ct_s[t] = c;
        qt_s[t] = so * tanhf(c);
      }
      __syncthreads();
    }
  }

  // ---------------- phase 3: DuelingNet ----------------
  // encoded = [attended(64), qt(64)]  (zeros when L==0, matching reference)
  {
    float x = bs1[t];
    for (int k = 0; k < E; ++k) x = fmaf(att_s[k], Ws1[k * SHD + t], x);
    for (int k = 0; k < H; ++k) x = fmaf(qt_s[k], Ws1[(E + k) * SHD + t], x);
    t1_s[t] = fmaxf(x, 0.f);
  }
  __syncthreads();
  if (t < SD) {
    float x = bs2[t];
    for (int k = 0; k < SHD; ++k) x = fmaf(t1_s[k], Ws2[k * SD + t], x);
    sh_s[t] = fmaxf(x, 0.f);
  }
  __syncthreads();
  if (t < SD) {
    float x = bp1[t];
    for (int k = 0; k < SD; ++k) x = fmaf(sh_s[k], Wp1[k * SD + t], x);
    a1_s[t] = fmaxf(x, 0.f);
  } else {
    const int tt = t - SD;
    float x = bv1[tt];
    for (int k = 0; k < SD; ++k) x = fmaf(sh_s[k], Wv1[k * SD + tt], x);
    v1_s[tt] = fmaxf(x, 0.f);
  }
  __syncthreads();
  if (wid == 0) {   // v = v1 @ Wv2 + bv2 (128-dot via wave 0)
    float vv = fmaf(v1_s[lane], Wv2[lane], v1_s[lane + 64] * Wv2[lane + 64]);
    #pragma unroll
    for (int d = 32; d > 0; d >>= 1) vv += __shfl_xor(vv, d);
    if (lane == 0) v_scalar = vv + bv2[0];
  }
  // adv: one column per thread (+ col 256 on thread 0)
  float adv = bp2[t];
  for (int k = 0; k < SD; ++k) adv = fmaf(a1_s[k], Wp2[k * NA + t], adv);
  float adv2 = 0.f;
  if (t == 0) {
    adv2 = bp2[NA - 1];
    for (int k = 0; k < SD; ++k) adv2 = fmaf(a1_s[k], Wp2[k * NA + (NA - 1)], adv2);
  }
  float ssum = adv + adv2;
  #pragma unroll
  for (int d = 32; d > 0; d >>= 1) ssum += __shfl_xor(ssum, d);
  if (lane == 0) wredf[wid] = ssum;
  __syncthreads();
  const float mean = (wredf[0] + wredf[1] + wredf[2] + wredf[3]) * (1.f / (float)NA);
  const float vv = v_scalar;
  out[b * NA + t] = vv + adv - mean;
  if (t == 0) out[b * NA + (NA - 1)] = vv + adv2 - mean;
}

}  // namespace

extern "C" void kernel_launch(void* const* d_in, const int* in_sizes, int n_in,
                              void* d_out, int out_size, void* d_ws, size_t ws_size,
                              hipStream_t stream) {
  const float* state    = (const float*)d_in[0];
  const int*   acquired = (const int*)d_in[1];
  const float* We1 = (const float*)d_in[2];
  const float* be1 = (const float*)d_in[3];
  const float* We2 = (const float*)d_in[4];
  const float* be2 = (const float*)d_in[5];
  const float* Wih = (const float*)d_in[6];
  const float* Whh = (const float*)d_in[7];
  const float* bih = (const float*)d_in[8];
  const float* bhh = (const float*)d_in[9];
  const float* Ws1 = (const float*)d_in[10];
  const float* bs1 = (const float*)d_in[11];
  const float* Ws2 = (const float*)d_in[12];
  const float* bs2 = (const float*)d_in[13];
  const float* Wp1 = (const float*)d_in[14];
  const float* bp1 = (const float*)d_in[15];
  const float* Wp2 = (const float*)d_in[16];
  const float* bp2 = (const float*)d_in[17];
  const float* Wv1 = (const float*)d_in[18];
  const float* bv1 = (const float*)d_in[19];
  const float* Wv2 = (const float*)d_in[20];
  const float* bv2 = (const float*)d_in[21];
  float* out = (float*)d_out;

  const int Bn = in_sizes[0] / NF;   // 2048
  hipLaunchKernelGGL(seqnet, dim3(Bn), dim3(256), 0, stream,
                     state, acquired, We1, be1, We2, be2, Wih, Whh, bih, bhh,
                     Ws1, bs1, Ws2, bs2, Wp1, bp1, Wp2, bp2, Wv1, bv1, Wv2, bv2,
                     out);
}